// Round 1
// baseline (42.548 us; speedup 1.0000x reference)
//
#include <hip/hip_runtime.h>
#include <math.h>

#define N_STATE 32

// One wave (64 threads) per block. Each block handles one (row d, L-chunk c).
// Thread t computes K[d, l0 + 64*k] for k = 0..steps-1 via the complex
// geometric recurrence p_n <- p_n * m_n with m_n = z_n^64, p_n init = G_n * z_n^l0.
// Stride-64 l-assignment => the wave's 64 lanes store 64 consecutive floats
// per step (fully coalesced 256B stores).
template <int S_CHUNKS>
__global__ __launch_bounds__(64, 2) void s4d_kernel(
    const float* __restrict__ log_A_real,  // (D,N)
    const float* __restrict__ A_imag,      // (D,N)
    const float* __restrict__ B,           // (D,N,2)
    const float* __restrict__ C,           // (D,N,2)
    const float* __restrict__ log_dt,      // (D,)
    float* __restrict__ K,                 // (D,L)
    int L) {
  const int bid = blockIdx.x;
  const int d = bid / S_CHUNKS;
  const int c = bid - d * S_CHUNKS;
  const int t = threadIdx.x;  // 0..63
  const int Lc = L / S_CHUNKS;
  const int steps = Lc >> 6;  // Lc / 64
  const int l0 = c * Lc + t;

  __shared__ float s_wr[N_STATE], s_wi[N_STATE];
  __shared__ float s_mr[N_STATE], s_mi[N_STATE];
  __shared__ float s_gr[N_STATE], s_gi[N_STATE];

  // dt = softplus(log_dt[d]); log_dt in [-6.9, -2.3] so expf is safe.
  const float dt = log1pf(expf(log_dt[d]));

  // Row-shared per-n quantities: computed once by lanes 0..31 into LDS.
  if (t < N_STATE) {
    const int n = t;
    const int idx = d * N_STATE + n;
    const float wr = -dt * log1pf(expf(log_A_real[idx]));  // dt * A_real
    const float wi = dt * A_imag[idx];                     // dt * A_imag
    const float br = B[2 * idx], bi = B[2 * idx + 1];
    const float cr = C[2 * idx], ci = C[2 * idx + 1];
    s_gr[n] = cr * br - ci * bi;  // Re(Cc*Bc)
    s_gi[n] = cr * bi + ci * br;  // Im(Cc*Bc)
    s_wr[n] = wr;
    s_wi[n] = wi;
    // m = z^64 = exp(64*w)
    const float em = expf(wr * 64.0f);
    float sm, cm;
    sincosf(wi * 64.0f, &sm, &cm);
    s_mr[n] = em * cm;
    s_mi[n] = em * sm;
  }
  __syncthreads();

  // Per-thread state init: p_n = G_n * z_n^l0 (accurate expf/sincosf; phase
  // <= ~1287 rad, sincosf does proper range reduction).
  float pr[N_STATE], pq[N_STATE], mr[N_STATE], mi[N_STATE];
  const float fl0 = (float)l0;
#pragma unroll
  for (int n = 0; n < N_STATE; ++n) {
    const float e0 = expf(s_wr[n] * fl0);
    float sn, cs;
    sincosf(s_wi[n] * fl0, &sn, &cs);
    const float zr = e0 * cs, zi = e0 * sn;
    const float gr = s_gr[n], gi = s_gi[n];
    pr[n] = gr * zr - gi * zi;
    pq[n] = gr * zi + gi * zr;
    mr[n] = s_mr[n];
    mi[n] = s_mi[n];
  }

  float* out = K + (size_t)d * L + l0;
  for (int k = 0; k < steps; ++k) {
    // K[d, l0+64k] = sum_n Re(p_n); 4-way partial sums to shorten the chain.
    float a0 = 0.f, a1 = 0.f, a2 = 0.f, a3 = 0.f;
#pragma unroll
    for (int n = 0; n < N_STATE; n += 4) {
      a0 += pr[n];
      a1 += pr[n + 1];
      a2 += pr[n + 2];
      a3 += pr[n + 3];
    }
    out[(size_t)k * 64] = (a0 + a1) + (a2 + a3);
    // p <- p * m (32 independent complex mults; high ILP)
#pragma unroll
    for (int n = 0; n < N_STATE; ++n) {
      const float nr = pr[n] * mr[n] - pq[n] * mi[n];
      const float ni = pr[n] * mi[n] + pq[n] * mr[n];
      pr[n] = nr;
      pq[n] = ni;
    }
  }
}

extern "C" void kernel_launch(void* const* d_in, const int* in_sizes, int n_in,
                              void* d_out, int out_size, void* d_ws,
                              size_t ws_size, hipStream_t stream) {
  const float* log_A_real = (const float*)d_in[0];
  const float* A_imag = (const float*)d_in[1];
  const float* B = (const float*)d_in[2];
  const float* C = (const float*)d_in[3];
  const float* log_dt = (const float*)d_in[4];
  float* K = (float*)d_out;

  const int D = in_sizes[4];      // 1024
  const int L = out_size / D;     // 4096

  constexpr int S_CHUNKS = 2;     // 2 chunks/row -> 2048 one-wave blocks
  dim3 grid(D * S_CHUNKS), block(64);
  hipLaunchKernelGGL(s4d_kernel<S_CHUNKS>, grid, block, 0, stream,
                     log_A_real, A_imag, B, C, log_dt, K, L);
}

// Round 2
// 25.218 us; speedup vs baseline: 1.6872x; 1.6872x over previous
//
#include <hip/hip_runtime.h>
#include <math.h>

#define N_STATE 32

// One wave (64 threads) per block; block = (row d, L-chunk c).
// Thread t computes K[d, l0 + 64*k] via complex geometric recurrence
// p_n <- p_n * m_n, m_n = z_n^64, init p_n = G_n * z_n^l0 using HW
// exp2/sin/cos (phase tracked in revolutions: v_sin_f32 input is revs).
// Multipliers m are wave-uniform -> forced to SGPRs via readfirstlane so
// per-lane state is only pr/pq (64 VGPRs) -> ~6 waves/SIMD.
template <int S_CHUNKS>
__global__ __launch_bounds__(64) void s4d_kernel(
    const float* __restrict__ log_A_real,  // (D,N)
    const float* __restrict__ A_imag,      // (D,N)
    const float* __restrict__ B,           // (D,N,2)
    const float* __restrict__ C,           // (D,N,2)
    const float* __restrict__ log_dt,      // (D,)
    float* __restrict__ K,                 // (D,L)
    int L) {
  const int bid = blockIdx.x;
  const int d = bid / S_CHUNKS;
  const int c = bid - d * S_CHUNKS;
  const int t = threadIdx.x;  // 0..63
  const int Lc = L / S_CHUNKS;
  const int steps = Lc >> 6;  // Lc / 64
  const int l0 = c * Lc + t;

  __shared__ float s_wr_l2e[N_STATE];  // dt*A_real * log2(e)
  __shared__ float s_wi_rev[N_STATE];  // dt*A_imag / (2*pi)
  __shared__ float s_mr[N_STATE], s_mi[N_STATE];  // m = z^64
  __shared__ float s_gr[N_STATE], s_gi[N_STATE];  // G = Cc*Bc

  const float dt = log1pf(expf(log_dt[d]));  // softplus, arg in [-6.9,-2.3]

  if (t < N_STATE) {
    const int n = t;
    const int idx = d * N_STATE + n;
    const float wr = -dt * log1pf(expf(log_A_real[idx]));  // dt*A_real (<0)
    const float wi = dt * A_imag[idx];                     // dt*A_imag (>=0)
    const float wr_l2e = wr * 1.4426950408889634f;
    const float wi_rev = wi * 0.15915494309189535f;
    s_wr_l2e[n] = wr_l2e;
    s_wi_rev[n] = wi_rev;
    const float br = B[2 * idx], bi = B[2 * idx + 1];
    const float cr = C[2 * idx], ci = C[2 * idx + 1];
    s_gr[n] = cr * br - ci * bi;
    s_gi[n] = cr * bi + ci * br;
    // m = z^64 = exp2(64*wr_l2e) * cis(2*pi*fract(64*wi_rev))
    const float em = __builtin_amdgcn_exp2f(wr_l2e * 64.0f);
    const float phm = __builtin_amdgcn_fractf(wi_rev * 64.0f);
    s_mr[n] = em * __builtin_amdgcn_cosf(phm);
    s_mi[n] = em * __builtin_amdgcn_sinf(phm);
  }
  __syncthreads();

  // Wave-uniform multipliers -> SGPRs (readfirstlane); v_mul/v_fma can take
  // one SGPR operand, so the inner loop stays legal.
  float mrv[N_STATE], miv[N_STATE];
#pragma unroll
  for (int n = 0; n < N_STATE; ++n) {
    mrv[n] = __uint_as_float(__builtin_amdgcn_readfirstlane(__float_as_uint(s_mr[n])));
    miv[n] = __uint_as_float(__builtin_amdgcn_readfirstlane(__float_as_uint(s_mi[n])));
  }

  // Per-lane init: p_n = G_n * z_n^l0 via HW exp2/sin/cos (phase in revs;
  // |wi_rev*l0| <= ~205, fp32 product error ~1e-5 rev -> fine).
  float pr[N_STATE], pq[N_STATE];
  const float fl0 = (float)l0;
#pragma unroll
  for (int n = 0; n < N_STATE; ++n) {
    const float e0 = __builtin_amdgcn_exp2f(s_wr_l2e[n] * fl0);
    const float ph = __builtin_amdgcn_fractf(s_wi_rev[n] * fl0);
    const float cs = __builtin_amdgcn_cosf(ph);
    const float sn = __builtin_amdgcn_sinf(ph);
    const float zr = e0 * cs, zi = e0 * sn;
    const float gr = s_gr[n], gi = s_gi[n];
    pr[n] = gr * zr - gi * zi;
    pq[n] = gr * zi + gi * zr;
  }

  float* out = K + (size_t)d * L + l0;
#pragma unroll 4
  for (int k = 0; k < steps; ++k) {
    float a0 = 0.f, a1 = 0.f, a2 = 0.f, a3 = 0.f;
#pragma unroll
    for (int n = 0; n < N_STATE; n += 4) {
      a0 += pr[n];
      a1 += pr[n + 1];
      a2 += pr[n + 2];
      a3 += pr[n + 3];
    }
    __builtin_nontemporal_store((a0 + a1) + (a2 + a3), out);
    out += 64;
#pragma unroll
    for (int n = 0; n < N_STATE; ++n) {
      const float nr = pr[n] * mrv[n] - pq[n] * miv[n];
      const float ni = pr[n] * miv[n] + pq[n] * mrv[n];
      pr[n] = nr;
      pq[n] = ni;
    }
  }
}

extern "C" void kernel_launch(void* const* d_in, const int* in_sizes, int n_in,
                              void* d_out, int out_size, void* d_ws,
                              size_t ws_size, hipStream_t stream) {
  const float* log_A_real = (const float*)d_in[0];
  const float* A_imag = (const float*)d_in[1];
  const float* B = (const float*)d_in[2];
  const float* C = (const float*)d_in[3];
  const float* log_dt = (const float*)d_in[4];
  float* K = (float*)d_out;

  const int D = in_sizes[4];   // 1024
  const int L = out_size / D;  // 4096

  constexpr int S_CHUNKS = 4;  // 4096 one-wave blocks -> 4+/SIMD
  dim3 grid(D * S_CHUNKS), block(64);
  hipLaunchKernelGGL(s4d_kernel<S_CHUNKS>, grid, block, 0, stream,
                     log_A_real, A_imag, B, C, log_dt, K, L);
}

// Round 3
// 11.692 us; speedup vs baseline: 3.6390x; 2.1569x over previous
//
#include <hip/hip_runtime.h>
#include <math.h>

#define N_STATE 32

typedef _Float16 f16;
typedef f16 f16x8 __attribute__((ext_vector_type(8)));
typedef float f32x4 __attribute__((ext_vector_type(4)));

// Swizzled byte offset inside a [64 rows][64 f16] table (128 B rows).
// XOR of (row&7) into byte bits 4-6 spreads the column-slice reads
// (ds_read_b128 at fixed k, varying row) across banks. Same function used
// for writes and reads -> bijective & consistent (rule #21).
__device__ __forceinline__ unsigned swz(int row, int byte_in_row) {
  return (unsigned)(((row << 7) + byte_in_row) ^ ((row & 7) << 4));
}

// One block (256 threads = 4 waves) per row d. out(64x64) = U(64x64)*V(64x64):
//   K[d, 64a+b] = sum_k U[a,k] V[k,b],
//   U[a,2n]=Re(G M^a), U[a,2n+1]=-Im(G M^a), V[2n,b]=Re(z^b), V[2n+1,b]=Im(z^b)
// with z=exp(dt*A), M=z^64, G=Cc*Bc. f16 operands, fp32 MFMA accumulate.
// k-mapping assumption (k = 8*(lane>>4)+e per 32-k-half) is applied to BOTH
// operands, so any consistent k-permutation yields the same contraction.
__global__ __launch_bounds__(256) void s4d_mfma_kernel(
    const float* __restrict__ log_A_real,  // (D,N)
    const float* __restrict__ A_imag,      // (D,N)
    const float* __restrict__ Bp,          // (D,N,2)
    const float* __restrict__ Cp,          // (D,N,2)
    const float* __restrict__ log_dt,      // (D,)
    float* __restrict__ K,                 // (D,L), L=4096
    int L) {
  const int d = blockIdx.x;
  const int tid = threadIdx.x;

  __shared__ float s_wrl2e[N_STATE], s_wirev[N_STATE];
  __shared__ float s_gr[N_STATE], s_gi[N_STATE];
  __shared__ __align__(16) f16 s_U[64 * 64];  // [a][k] swizzled, 8 KB
  __shared__ __align__(16) f16 s_V[64 * 64];  // [b][k] swizzled, 8 KB

  // Phase 1: per-n row constants.
  if (tid < N_STATE) {
    const int n = tid;
    const int idx = d * N_STATE + n;
    const float dt = log1pf(expf(log_dt[d]));            // softplus
    const float wr = -dt * log1pf(expf(log_A_real[idx]));  // dt*A_real < 0
    const float wi = dt * A_imag[idx];                     // dt*A_imag >= 0
    s_wrl2e[n] = wr * 1.4426950408889634f;   // log2 scale for v_exp_f32
    s_wirev[n] = wi * 0.15915494309189535f;  // revolutions for v_sin/cos
    const float br = Bp[2 * idx], bi = Bp[2 * idx + 1];
    const float cr = Cp[2 * idx], ci = Cp[2 * idx + 1];
    s_gr[n] = cr * br - ci * bi;
    s_gi[n] = cr * bi + ci * br;
  }
  __syncthreads();

  // Phase 2: build U (threads 0-127) and V (threads 128-255); 16 evals each.
  {
    const int uh = tid >> 7;      // 0 -> U table, 1 -> V table
    const int idx = tid & 127;
    const int row = idx & 63;     // a (for U) or b (for V)
    const int nh = idx >> 6;      // n half: [16*nh, 16*nh+16)
    // U needs z^(64*row) = M^row; V needs z^row.
    const float sf = uh ? (float)row : (float)(row * 64);
    f16* tab = uh ? s_V : s_U;
    char* base = (char*)tab;
#pragma unroll
    for (int j = 0; j < 16; ++j) {
      const int n = nh * 16 + j;
      const float er = __builtin_amdgcn_exp2f(s_wrl2e[n] * sf);
      const float ph = __builtin_amdgcn_fractf(s_wirev[n] * sf);
      const float cs = __builtin_amdgcn_cosf(ph);  // v_cos: revolutions
      const float sn = __builtin_amdgcn_sinf(ph);
      const float zr = er * cs, zi = er * sn;
      float u0, u1;
      if (uh == 0) {
        u0 = s_gr[n] * zr - s_gi[n] * zi;     //  Re(G M^a)
        u1 = -(s_gr[n] * zi + s_gi[n] * zr);  // -Im(G M^a)
      } else {
        u0 = zr;  // Re(z^b)
        u1 = zi;  // Im(z^b)
      }
      union { f16 h[2]; unsigned u; } pk;
      pk.h[0] = (f16)u0;
      pk.h[1] = (f16)u1;
      *(unsigned*)(base + swz(row, n * 4)) = pk.u;
    }
  }
  __syncthreads();

  // Phase 3: wave wid owns output rows a in [16*wid, 16*wid+16).
  const int wid = tid >> 6;
  const int lane = tid & 63;
  const int r = lane & 15;   // row (A) / col (B) / col (D)
  const int g = lane >> 4;   // k-group

  f16x8 afrag[2];
#pragma unroll
  for (int kt = 0; kt < 2; ++kt)
    afrag[kt] = *(const f16x8*)((const char*)s_U +
                                swz(16 * wid + r, kt * 64 + g * 16));

  f32x4 acc[4];
#pragma unroll
  for (int nt = 0; nt < 4; ++nt) acc[nt] = (f32x4){0.f, 0.f, 0.f, 0.f};

#pragma unroll
  for (int nt = 0; nt < 4; ++nt) {
#pragma unroll
    for (int kt = 0; kt < 2; ++kt) {
      const f16x8 bfrag = *(const f16x8*)((const char*)s_V +
                                          swz(16 * nt + r, kt * 64 + g * 16));
      acc[nt] =
          __builtin_amdgcn_mfma_f32_16x16x32_f16(afrag[kt], bfrag, acc[nt], 0, 0, 0);
    }
  }

  // Epilogue: D layout col=lane&15, row=4*(lane>>4)+reg (verified m89/m91).
  float* outd = K + (size_t)d * L;
#pragma unroll
  for (int nt = 0; nt < 4; ++nt) {
#pragma unroll
    for (int rr = 0; rr < 4; ++rr) {
      const int l = (16 * wid + 4 * g + rr) * 64 + 16 * nt + r;
      __builtin_nontemporal_store(acc[nt][rr], outd + l);
    }
  }
}

extern "C" void kernel_launch(void* const* d_in, const int* in_sizes, int n_in,
                              void* d_out, int out_size, void* d_ws,
                              size_t ws_size, hipStream_t stream) {
  const float* log_A_real = (const float*)d_in[0];
  const float* A_imag = (const float*)d_in[1];
  const float* B = (const float*)d_in[2];
  const float* C = (const float*)d_in[3];
  const float* log_dt = (const float*)d_in[4];
  float* K = (float*)d_out;

  const int D = in_sizes[4];   // 1024
  const int L = out_size / D;  // 4096 (kernel assumes 64x64 factorization)

  dim3 grid(D), block(256);
  hipLaunchKernelGGL(s4d_mfma_kernel, grid, block, 0, stream, log_A_real,
                     A_imag, B, C, log_dt, K, L);
}